// Round 10
// baseline (475.239 us; speedup 1.0000x reference)
//
#include <hip/hip_runtime.h>
#include <math.h>

#define HEADS 4
#define HD 32
#define DIM 128
#define NEG_SLOPE 0.2f
#define EPS_SM 1e-8f
#define EPS_LN 1e-5f
#define GROWS 64
#define SH1 9              // 512 segments per coarse bin; NBIN = ceil(2N/512) <= 512
#define PB 128             // partition blocks

__device__ __forceinline__ float lrelu(float x) { return x > 0.f ? x : NEG_SLOPE * x; }
__device__ __forceinline__ unsigned bf16rne(float x) {
    unsigned b = __float_as_uint(x);
    return (b + 0x7fffu + ((b >> 16) & 1u)) >> 16;
}
__device__ __forceinline__ float2 pkfma(float2 v, float2 w, float2 c) {
    return make_float2(fmaf(v.x, w.x, c.x), fmaf(v.y, w.y, c.y));
}

template<int LIM> __device__ __forceinline__ void rsum4(float& a, float& b, float& c, float& d) {
#pragma unroll
    for (int s = 1; s < LIM; s <<= 1) {
        a += __shfl_xor(a, s, 64);
        b += __shfl_xor(b, s, 64);
        c += __shfl_xor(c, s, 64);
        d += __shfl_xor(d, s, 64);
    }
}

// ---------------- fused dual GEMM + attention dots + bf16 pack ----------------
// Prefetch staging: chunk kc+1's global loads issued before computing chunk kc.
__global__ __launch_bounds__(256) void dual_gemm_k(const float* __restrict__ h,
                                                   const float* __restrict__ W,
                                                   const float* __restrict__ V,
                                                   const float* __restrict__ a_in,
                                                   const float* __restrict__ a_out,
                                                   float* __restrict__ h_self,
                                                   unsigned* __restrict__ hp_pk,
                                                   float* __restrict__ pA0, float* __restrict__ pA1,
                                                   float* __restrict__ pB0, float* __restrict__ pB1,
                                                   int N) {
    __shared__ float As[32][GROWS];
    __shared__ float Ws[32][DIM];
    __shared__ float Vs[32][DIM];
    __shared__ float ainL[256], aoutL[256];
    const int tid = threadIdx.x;
    const int cg = tid & 15;
    const int rg = tid >> 4;
    const int row0 = blockIdx.x * GROWS;

    ainL[tid] = a_in[tid];
    aoutL[tid] = a_out[tid];

    float accP[4][8], accS[4][8];
#pragma unroll
    for (int r = 0; r < 4; ++r)
#pragma unroll
        for (int c = 0; c < 8; ++c) { accP[r][c] = 0.f; accS[r][c] = 0.f; }

    float4 pha[2], pw[4], pv[4];
    auto load_chunk = [&](int kc) {
#pragma unroll
        for (int p = 0; p < 2; ++p) {
            int f = tid + p * 256;
            int r = f >> 3, c4 = f & 7;
            float4 v = make_float4(0.f, 0.f, 0.f, 0.f);
            if (row0 + r < N) v = ((const float4*)h)[(size_t)(row0 + r) * 32 + kc * 8 + c4];
            pha[p] = v;
        }
#pragma unroll
        for (int p = 0; p < 4; ++p) {
            int f = tid + p * 256;
            int lk = f >> 5, c4 = f & 31;
            pw[p] = ((const float4*)W)[(size_t)(kc * 32 + lk) * 32 + c4];
            pv[p] = ((const float4*)V)[(size_t)(kc * 32 + lk) * 32 + c4];
        }
    };

    load_chunk(0);
    for (int kc = 0; kc < 4; ++kc) {
        // write staged regs -> LDS
#pragma unroll
        for (int p = 0; p < 2; ++p) {
            int f = tid + p * 256;
            int r = f >> 3, c4 = f & 7;
            As[c4 * 4 + 0][r] = pha[p].x;
            As[c4 * 4 + 1][r] = pha[p].y;
            As[c4 * 4 + 2][r] = pha[p].z;
            As[c4 * 4 + 3][r] = pha[p].w;
        }
#pragma unroll
        for (int p = 0; p < 4; ++p) {
            int f = tid + p * 256;
            int lk = f >> 5, c4 = f & 31;
            ((float4*)&Ws[lk][0])[c4] = pw[p];
            ((float4*)&Vs[lk][0])[c4] = pv[p];
        }
        __syncthreads();
        if (kc < 3) load_chunk(kc + 1);   // overlap next chunk's loads with compute
#pragma unroll
        for (int kk = 0; kk < 32; ++kk) {
            float4 a = *(const float4*)&As[kk][rg * 4];
            float4 w0 = *(const float4*)&Ws[kk][cg * 8];
            float4 w1 = *(const float4*)&Ws[kk][cg * 8 + 4];
            float4 v0 = *(const float4*)&Vs[kk][cg * 8];
            float4 v1 = *(const float4*)&Vs[kk][cg * 8 + 4];
            float av[4] = {a.x, a.y, a.z, a.w};
            float wv[8] = {w0.x, w0.y, w0.z, w0.w, w1.x, w1.y, w1.z, w1.w};
            float vv[8] = {v0.x, v0.y, v0.z, v0.w, v1.x, v1.y, v1.z, v1.w};
#pragma unroll
            for (int r = 0; r < 4; ++r)
#pragma unroll
                for (int c = 0; c < 8; ++c) {
                    accP[r][c] += av[r] * wv[c];
                    accS[r][c] += av[r] * vv[c];
                }
        }
        __syncthreads();
    }

    // ---- epilogue 1: h_self (f32) ----
#pragma unroll
    for (int r = 0; r < 4; ++r) {
        int row = row0 + rg * 4 + r;
        if (row < N) {
            float4 s0 = make_float4(accS[r][0], accS[r][1], accS[r][2], accS[r][3]);
            float4 s1 = make_float4(accS[r][4], accS[r][5], accS[r][6], accS[r][7]);
            ((float4*)h_self)[(size_t)row * 32 + cg * 2] = s0;
            ((float4*)h_self)[(size_t)row * 32 + cg * 2 + 1] = s1;
        }
    }

    // ---- epilogue 2: attention dot tables ----
    const int head = cg >> 2, qi = cg & 3;
#pragma unroll
    for (int r = 0; r < 4; ++r) {
        float d0 = 0.f, d1 = 0.f, d2 = 0.f, d3 = 0.f;
#pragma unroll
        for (int c = 0; c < 8; ++c) {
            float v = accP[r][c];
            int k = head * 64 + qi * 8 + c;
            d0 += v * ainL[k];
            d1 += v * ainL[k + 32];
            d2 += v * aoutL[k];
            d3 += v * aoutL[k + 32];
        }
        d0 += __shfl_xor(d0, 1, 64); d0 += __shfl_xor(d0, 2, 64);
        d1 += __shfl_xor(d1, 1, 64); d1 += __shfl_xor(d1, 2, 64);
        d2 += __shfl_xor(d2, 1, 64); d2 += __shfl_xor(d2, 2, 64);
        d3 += __shfl_xor(d3, 1, 64); d3 += __shfl_xor(d3, 2, 64);
        if (qi == 0) {
            int row = row0 + rg * 4 + r;
            if (row < N) {
                pA0[row * 4 + head] = d0;
                pA1[row * 4 + head] = d1;
                pB0[row * 4 + head] = d2;
                pB1[row * 4 + head] = d3;
            }
        }
    }

    // ---- epilogue 3: bf16 pack (c, c+64) via LDS half-exchange ----
    __syncthreads();
    float* lds2 = &Ws[0][0];
    if (cg >= 8) {
#pragma unroll
        for (int r = 0; r < 4; ++r) {
            int rl = rg * 4 + r;
#pragma unroll
            for (int c = 0; c < 8; ++c) lds2[rl * 64 + (cg - 8) * 8 + c] = accP[r][c];
        }
    }
    __syncthreads();
    if (cg < 8) {
#pragma unroll
        for (int r = 0; r < 4; ++r) {
            int rl = rg * 4 + r;
            int row = row0 + rl;
            if (row < N) {
                unsigned pks[8];
#pragma unroll
                for (int c = 0; c < 8; ++c)
                    pks[c] = bf16rne(accP[r][c]) | (bf16rne(lds2[rl * 64 + cg * 8 + c]) << 16);
                uint4* dst = (uint4*)(hp_pk + (size_t)row * 64 + cg * 8);
                dst[0] = make_uint4(pks[0], pks[1], pks[2], pks[3]);
                dst[1] = make_uint4(pks[4], pks[5], pks[6], pks[7]);
            }
        }
    }
}

// ---------------- deterministic two-level CSR build (no global atomics) ----------------
__global__ __launch_bounds__(256) void part1a_k(const int* __restrict__ ei, int* __restrict__ cntmat,
                                                int E, int N, int NBIN) {
    __shared__ int lcnt[512];
    const int t = threadIdx.x;
    const int CH = (E + gridDim.x - 1) / gridDim.x;
    const int e0 = blockIdx.x * CH;
    const int e1 = min(e0 + CH, E);
    for (int i = t; i < 512; i += 256) lcnt[i] = 0;
    __syncthreads();
    for (int e = e0 + t; e < e1; e += 256) {
        int s = ei[e], d = ei[E + e];
        atomicAdd(&lcnt[d >> SH1], 1);
        atomicAdd(&lcnt[(N + s) >> SH1], 1);
    }
    __syncthreads();
    for (int i = t; i < NBIN; i += 256) cntmat[i * PB + blockIdx.x] = lcnt[i];
}

__global__ __launch_bounds__(128) void scanB_k(const int* __restrict__ cntmat,
                                               int* __restrict__ blkoff, int* __restrict__ btot) {
    __shared__ int ls[PB];
    const int bin = blockIdx.x;
    const int t = threadIdx.x;
    int v = cntmat[bin * PB + t];
    ls[t] = v;
    __syncthreads();
#pragma unroll
    for (int d = 1; d < PB; d <<= 1) {
        int u = (t >= d) ? ls[t - d] : 0;
        __syncthreads();
        ls[t] += u;
        __syncthreads();
    }
    blkoff[bin * PB + t] = ls[t] - v;
    if (t == PB - 1) btot[bin] = ls[t];
}

__global__ __launch_bounds__(256) void scanC_k(const int* __restrict__ btot,
                                               int* __restrict__ bbase, int NBIN, int twoE) {
    __shared__ int ls[256];
    int t = threadIdx.x;
    int i0 = 2 * t, i1 = 2 * t + 1;
    int v0 = (i0 < NBIN) ? btot[i0] : 0;
    int v1 = (i1 < NBIN) ? btot[i1] : 0;
    int pair = v0 + v1;
    ls[t] = pair;
    __syncthreads();
#pragma unroll
    for (int d = 1; d < 256; d <<= 1) {
        int u = (t >= d) ? ls[t - d] : 0;
        __syncthreads();
        ls[t] += u;
        __syncthreads();
    }
    int excl = ls[t] - pair;
    if (i0 < NBIN) bbase[i0] = excl;
    if (i1 < NBIN) bbase[i1] = excl + v0;
    if (t == 0) bbase[NBIN] = twoE;
}

__global__ __launch_bounds__(256) void part1b_k(const int* __restrict__ ei,
                                                const int* __restrict__ bbase,
                                                const int* __restrict__ blkoff,
                                                unsigned* __restrict__ rec, int E, int N, int NBIN) {
    __shared__ int gb[512];
    __shared__ int lcur[512];
    const int t = threadIdx.x;
    const int CH = (E + gridDim.x - 1) / gridDim.x;
    const int e0 = blockIdx.x * CH;
    const int e1 = min(e0 + CH, E);
    for (int i = t; i < 512; i += 256) lcur[i] = 0;
    for (int i = t; i < NBIN; i += 256) gb[i] = bbase[i] + blkoff[i * PB + blockIdx.x];
    __syncthreads();
    for (int e = e0 + t; e < e1; e += 256) {
        int s = ei[e], d = ei[E + e];
        int b1 = d >> SH1;
        int r1 = atomicAdd(&lcur[b1], 1);
        rec[gb[b1] + r1] = (unsigned)s | ((unsigned)(d & 511) << 20);
        int so = N + s;
        int b2 = so >> SH1;
        int r2 = atomicAdd(&lcur[b2], 1);
        rec[gb[b2] + r2] = (unsigned)d | ((unsigned)(so & 511) << 20);
    }
}

__global__ __launch_bounds__(256) void build2_k(const unsigned* __restrict__ rec,
                                                const int* __restrict__ bbase,
                                                int* __restrict__ off, int* __restrict__ csr,
                                                int M, int twoE, int NBIN) {
    __shared__ int lcnt[512];
    __shared__ int lcur[512];
    __shared__ int ls[256];
    const int b = blockIdx.x;
    const int t = threadIdx.x;
    const int base = bbase[b];
    const int cnt = bbase[b + 1] - base;
    const int seg0 = b << SH1;
    for (int i = t; i < 512; i += 256) lcnt[i] = 0;
    __syncthreads();
    for (int k = t; k < cnt; k += 256) atomicAdd(&lcnt[rec[base + k] >> 20], 1);
    __syncthreads();
    int v0 = lcnt[2 * t], v1 = lcnt[2 * t + 1];
    int pair = v0 + v1;
    ls[t] = pair;
    __syncthreads();
#pragma unroll
    for (int d = 1; d < 256; d <<= 1) {
        int u = (t >= d) ? ls[t - d] : 0;
        __syncthreads();
        ls[t] += u;
        __syncthreads();
    }
    int excl = ls[t] - pair;
    lcur[2 * t] = excl;
    lcur[2 * t + 1] = excl + v0;
    int sg = seg0 + 2 * t;
    if (sg < M) off[sg] = base + excl;
    if (sg + 1 < M) off[sg + 1] = base + excl + v0;
    if (b == NBIN - 1 && t == 0) off[M] = twoE;
    __syncthreads();
    for (int k = t; k < cnt; k += 256) {
        unsigned r = rec[base + k];
        int pos = atomicAdd(&lcur[r >> 20], 1);
        csr[base + pos] = (int)(r & 0xFFFFFu);
    }
}

// ---------------- fused: per-node softmax-aggregate + combine + LN ----------------
// No max pass: logits = lrelu(dot with 0.01-scaled attn vecs) are bounded |e| < ~1,
// so exp(e)/sum(exp(e)) == exp(e-m)/sum(exp(e-m)) exactly (algebraic identity), safe in f32.
// j-loop: 4 edges/iter via quarter-waves (16 lanes x dwordx4 = one 256B row).
__global__ __launch_bounds__(256) void node_aggr_ln_k(const unsigned* __restrict__ hp_pk,
                                                      const float* __restrict__ h_self,
                                                      const float* __restrict__ pA0, const float* __restrict__ pA1,
                                                      const float* __restrict__ pB0, const float* __restrict__ pB1,
                                                      const int* __restrict__ off, const int* __restrict__ csr,
                                                      const float* __restrict__ bias,
                                                      const float* __restrict__ gamma,
                                                      const float* __restrict__ beta,
                                                      float* __restrict__ out, int N) {
    __shared__ uint4 lw[4][64];   // entry j: {pkA(w0,w2), sid, pkB(w1,w3), sid}
    const int wave = threadIdx.x >> 6;
    const int lane = threadIdx.x & 63;
    const int n = blockIdx.x * 4 + wave;
    if (n >= N) return;
    const int l15 = lane & 15;
    const int q = lane >> 4;
    const unsigned lwoff = (unsigned)((q << 4) + ((l15 >> 3) << 3));
    const char* lwbase = (const char*)&lw[wave][0];
    const uint4* __restrict__ hpp4 = (const uint4*)hp_pk;   // row stride 16 uint4

    float2 a0 = make_float2(0.f, 0.f), a1 = make_float2(0.f, 0.f);
    float2 a2 = make_float2(0.f, 0.f), a3 = make_float2(0.f, 0.f);

#pragma unroll
    for (int dir = 0; dir < 2; ++dir) {
        const int seg = (dir == 0) ? n : N + n;
        const int beg = off[seg], end = off[seg + 1];
        const int len = end - beg;
        if (len == 0) continue;
        const float* __restrict__ p0 = (dir == 0) ? pA0 : pB0;
        const float* __restrict__ p1 = (dir == 0) ? pA1 : pB1;
        float4 r1 = ((const float4*)p1)[n];

        if (len <= 64) {
            int sid = 0;
            float w0 = 0.f, w1 = 0.f, w2 = 0.f, w3 = 0.f;
            if (lane < len) {
                sid = csr[beg + lane];
                float4 r0 = ((const float4*)p0)[sid];
                w0 = __expf(lrelu(r0.x + r1.x));
                w1 = __expf(lrelu(r0.y + r1.y));
                w2 = __expf(lrelu(r0.z + r1.z));
                w3 = __expf(lrelu(r0.w + r1.w));
            }
            float s0 = w0, s1 = w1, s2 = w2, s3 = w3;
            if (len <= 16)      rsum4<16>(s0, s1, s2, s3);
            else if (len <= 32) rsum4<32>(s0, s1, s2, s3);
            else                rsum4<64>(s0, s1, s2, s3);
            w0 *= 1.f / (s0 + EPS_SM);
            w1 *= 1.f / (s1 + EPS_SM);
            w2 *= 1.f / (s2 + EPS_SM);
            w3 *= 1.f / (s3 + EPS_SM);
            unsigned pkA = bf16rne(w0) | (bf16rne(w2) << 16);
            unsigned pkB = bf16rne(w1) | (bf16rne(w3) << 16);
            lw[wave][lane] = make_uint4(pkA, (unsigned)sid, pkB, (unsigned)sid);
            const int nt = (len + 3) >> 2;
#pragma unroll 2
            for (int t = 0; t < nt; ++t) {
                uint2 wv = *(const uint2*)(lwbase + t * 64 + lwoff);
                uint4 v = hpp4[((size_t)wv.y << 4) + l15];
                float2 w = make_float2(__uint_as_float(wv.x << 16),
                                       __uint_as_float(wv.x & 0xffff0000u));
                a0 = pkfma(make_float2(__uint_as_float(v.x << 16), __uint_as_float(v.x & 0xffff0000u)), w, a0);
                a1 = pkfma(make_float2(__uint_as_float(v.y << 16), __uint_as_float(v.y & 0xffff0000u)), w, a1);
                a2 = pkfma(make_float2(__uint_as_float(v.z << 16), __uint_as_float(v.z & 0xffff0000u)), w, a2);
                a3 = pkfma(make_float2(__uint_as_float(v.w << 16), __uint_as_float(v.w & 0xffff0000u)), w, a3);
            }
        } else {
            // rare: deg > 64 — sum pass, then chunked weight+gather pass
            float s0 = 0.f, s1 = 0.f, s2 = 0.f, s3 = 0.f;
            for (int base = beg; base < end; base += 64) {
                int j = base + lane;
                if (j < end) {
                    int sid = csr[j];
                    float4 r0 = ((const float4*)p0)[sid];
                    s0 += __expf(lrelu(r0.x + r1.x));
                    s1 += __expf(lrelu(r0.y + r1.y));
                    s2 += __expf(lrelu(r0.z + r1.z));
                    s3 += __expf(lrelu(r0.w + r1.w));
                }
            }
            rsum4<64>(s0, s1, s2, s3);
            const float is0 = 1.f / (s0 + EPS_SM);
            const float is1 = 1.f / (s1 + EPS_SM);
            const float is2 = 1.f / (s2 + EPS_SM);
            const float is3 = 1.f / (s3 + EPS_SM);
            for (int base = beg; base < end; base += 64) {
                int cnt = min(64, end - base);
                int sid = 0;
                float w0 = 0.f, w1 = 0.f, w2 = 0.f, w3 = 0.f;
                if (lane < cnt) {
                    sid = csr[base + lane];
                    float4 r0 = ((const float4*)p0)[sid];
                    w0 = __expf(lrelu(r0.x + r1.x)) * is0;
                    w1 = __expf(lrelu(r0.y + r1.y)) * is1;
                    w2 = __expf(lrelu(r0.z + r1.z)) * is2;
                    w3 = __expf(lrelu(r0.w + r1.w)) * is3;
                }
                unsigned pkA = bf16rne(w0) | (bf16rne(w2) << 16);
                unsigned pkB = bf16rne(w1) | (bf16rne(w3) << 16);
                lw[wave][lane] = make_uint4(pkA, (unsigned)sid, pkB, (unsigned)sid);
                const int nt = (cnt + 3) >> 2;
#pragma unroll 2
                for (int t = 0; t < nt; ++t) {
                    uint2 wv = *(const uint2*)(lwbase + t * 64 + lwoff);
                    uint4 v = hpp4[((size_t)wv.y << 4) + l15];
                    float2 w = make_float2(__uint_as_float(wv.x << 16),
                                           __uint_as_float(wv.x & 0xffff0000u));
                    a0 = pkfma(make_float2(__uint_as_float(v.x << 16), __uint_as_float(v.x & 0xffff0000u)), w, a0);
                    a1 = pkfma(make_float2(__uint_as_float(v.y << 16), __uint_as_float(v.y & 0xffff0000u)), w, a1);
                    a2 = pkfma(make_float2(__uint_as_float(v.z << 16), __uint_as_float(v.z & 0xffff0000u)), w, a2);
                    a3 = pkfma(make_float2(__uint_as_float(v.w << 16), __uint_as_float(v.w & 0xffff0000u)), w, a3);
                }
            }
        }
    }

    // merge quarter-wave partials (disjoint edge subsets)
#pragma unroll
    for (int s = 16; s < 64; s <<= 1) {
        a0.x += __shfl_xor(a0.x, s, 64); a0.y += __shfl_xor(a0.y, s, 64);
        a1.x += __shfl_xor(a1.x, s, 64); a1.y += __shfl_xor(a1.y, s, 64);
        a2.x += __shfl_xor(a2.x, s, 64); a2.y += __shfl_xor(a2.y, s, 64);
        a3.x += __shfl_xor(a3.x, s, 64); a3.y += __shfl_xor(a3.y, s, 64);
    }

    // combine + LayerNorm (lane holds channels 4*l15..+3 and +64..; duplicated across quarters)
    size_t bb = (size_t)n * DIM;
    float4 hs0 = *(const float4*)(h_self + bb + 4 * l15);
    float4 hs1 = *(const float4*)(h_self + bb + 64 + 4 * l15);
    float4 b0 = *(const float4*)(bias + 4 * l15);
    float4 b1 = *(const float4*)(bias + 64 + 4 * l15);
    float x0 = hs0.x + a0.x + b0.x;
    float x1 = hs0.y + a1.x + b0.y;
    float x2 = hs0.z + a2.x + b0.z;
    float x3 = hs0.w + a3.x + b0.w;
    float y0 = hs1.x + a0.y + b1.x;
    float y1 = hs1.y + a1.y + b1.y;
    float y2 = hs1.z + a2.y + b1.z;
    float y3 = hs1.w + a3.y + b1.w;
    float sum = x0 + x1 + x2 + x3 + y0 + y1 + y2 + y3;
    float sq = x0 * x0 + x1 * x1 + x2 * x2 + x3 * x3
             + y0 * y0 + y1 * y1 + y2 * y2 + y3 * y3;
#pragma unroll
    for (int m = 1; m < 64; m <<= 1) {
        sum += __shfl_xor(sum, m, 64);
        sq += __shfl_xor(sq, m, 64);
    }
    float mean = sum * (1.f / 512.f);          // each channel counted 4x
    float var = sq * (1.f / 512.f) - mean * mean;
    float inv = rsqrtf(var + EPS_LN);
    if (lane < 16) {
        float4 g0 = *(const float4*)(gamma + 4 * l15);
        float4 g1 = *(const float4*)(gamma + 64 + 4 * l15);
        float4 be0 = *(const float4*)(beta + 4 * l15);
        float4 be1 = *(const float4*)(beta + 64 + 4 * l15);
        float4 o0 = make_float4((x0 - mean) * inv * g0.x + be0.x,
                                (x1 - mean) * inv * g0.y + be0.y,
                                (x2 - mean) * inv * g0.z + be0.z,
                                (x3 - mean) * inv * g0.w + be0.w);
        float4 o1 = make_float4((y0 - mean) * inv * g1.x + be1.x,
                                (y1 - mean) * inv * g1.y + be1.y,
                                (y2 - mean) * inv * g1.z + be1.z,
                                (y3 - mean) * inv * g1.w + be1.w);
        *(float4*)(out + bb + 4 * l15) = o0;
        *(float4*)(out + bb + 64 + 4 * l15) = o1;
    }
}

extern "C" void kernel_launch(void* const* d_in, const int* in_sizes, int n_in,
                              void* d_out, int out_size, void* d_ws, size_t ws_size,
                              hipStream_t stream) {
    const float* h      = (const float*)d_in[0];
    const int*   ei     = (const int*)d_in[1];
    const float* W      = (const float*)d_in[2];
    const float* W_self = (const float*)d_in[3];
    const float* a_in   = (const float*)d_in[4];
    const float* a_out  = (const float*)d_in[5];
    const float* bias   = (const float*)d_in[6];
    const float* gamma  = (const float*)d_in[7];
    const float* beta   = (const float*)d_in[8];
    float* out = (float*)d_out;

    const int N = in_sizes[0] / DIM;
    const int E = in_sizes[1] / 2;
    const int M = 2 * N;
    const int NBIN = (M + (1 << SH1) - 1) >> SH1;
    const int twoE = 2 * E;

    // workspace layout
    float* ws = (float*)d_ws;
    size_t off_f = 0;
    float* h_self = ws + off_f; off_f += (size_t)N * DIM;
    unsigned* hp_pk = (unsigned*)(ws + off_f); off_f += (size_t)N * 64;
    float* pA0 = ws + off_f; off_f += (size_t)N * 4;
    float* pA1 = ws + off_f; off_f += (size_t)N * 4;
    float* pB0 = ws + off_f; off_f += (size_t)N * 4;
    float* pB1 = ws + off_f; off_f += (size_t)N * 4;
    int* ip = (int*)(ws + off_f);
    size_t off_i = 0;
    int* cntmat = ip + off_i; off_i += (size_t)NBIN * PB;
    int* blkoff = ip + off_i; off_i += (size_t)NBIN * PB;
    int* btot   = ip + off_i; off_i += NBIN;
    int* bbase  = ip + off_i; off_i += (size_t)NBIN + 1;
    int* off    = ip + off_i; off_i += (size_t)M + 1;
    unsigned* rec = (unsigned*)(ip + off_i); off_i += (size_t)twoE;
    int* csr    = ip + off_i; off_i += (size_t)twoE;

    // ---- deterministic two-level CSR build ----
    part1a_k<<<PB, 256, 0, stream>>>(ei, cntmat, E, N, NBIN);
    scanB_k<<<NBIN, PB, 0, stream>>>(cntmat, blkoff, btot);
    scanC_k<<<1, 256, 0, stream>>>(btot, bbase, NBIN, twoE);
    part1b_k<<<PB, 256, 0, stream>>>(ei, bbase, blkoff, rec, E, N, NBIN);
    build2_k<<<NBIN, 256, 0, stream>>>(rec, bbase, off, csr, M, twoE, NBIN);

    // ---- fused projections + dots + pack ----
    dual_gemm_k<<<(N + GROWS - 1) / GROWS, 256, 0, stream>>>(h, W, W_self, a_in, a_out,
                                                             h_self, hp_pk, pA0, pA1, pB0, pB1, N);

    // ---- fused aggregate + LN ----
    node_aggr_ln_k<<<(N + 3) / 4, 256, 0, stream>>>(hp_pk, h_self, pA0, pA1, pB0, pB1,
                                                    off, csr, bias, gamma, beta, out, N);
}